// Round 1
// 405.687 us; speedup vs baseline: 1.8345x; 1.8345x over previous
//
#include <hip/hip_runtime.h>
#include <hip/hip_bf16.h>

#define HH 448
#define WW 160
#define NPIX (HH*WW)

typedef unsigned long long u64;

__device__ __forceinline__ float leaky(float v) { return v >= 0.f ? v : 0.01f * v; }

// act is stored transposed: logical (w, c) -> float index with XOR block swizzle.
// Row = 128 floats (32 x 16B blocks); physical block = (c/4) ^ (w & 31).
__device__ __forceinline__ int actIdx(int w, int c) {
    return (w << 7) + ((((c >> 2) ^ (w & 31))) << 2) + (c & 3);
}

__device__ __forceinline__ void loadW(float4 wreg[8], const float4* __restrict__ src, int t) {
#pragma unroll
    for (int k = 0; k < 8; ++k) wreg[k] = src[t + (k << 9)];
}
__device__ __forceinline__ void storeW(const float4 wreg[8], float* wbuf, int t) {
#pragma unroll
    for (int k = 0; k < 8; ++k) reinterpret_cast<float4*>(wbuf)[t + (k << 9)] = wreg[k];
}

// One 128-row x 160-col pass: thread (og, ws) computes rows og*8..+7, cols ws*5..+4.
// Weight reads from wbuf are 2-address broadcasts; x reads are swizzled b128, bank-balanced.
// Accumulation is strictly ascending in c (bitwise-matches the previous passing kernel).
__device__ __forceinline__ void compute128(const float* act, const float* wbuf,
                                           const int wbase[5], const int wk[5],
                                           int og8, float acc[8][5])
{
#pragma unroll
    for (int a = 0; a < 8; ++a)
#pragma unroll
        for (int j = 0; j < 5; ++j) acc[a][j] = 0.f;
    const float* wr = wbuf + (og8 << 7);
#pragma unroll 2
    for (int cb = 0; cb < 32; ++cb) {
        float4 xv[5];
#pragma unroll
        for (int j = 0; j < 5; ++j)
            xv[j] = *reinterpret_cast<const float4*>(act + wbase[j] + ((cb ^ wk[j]) << 2));
#pragma unroll
        for (int a = 0; a < 8; ++a) {
            const float4 wv = *reinterpret_cast<const float4*>(wr + (a << 7) + (cb << 2));
#pragma unroll
            for (int j = 0; j < 5; ++j) {
                acc[a][j] = fmaf(wv.x, xv[j].x, acc[a][j]);
                acc[a][j] = fmaf(wv.y, xv[j].y, acc[a][j]);
                acc[a][j] = fmaf(wv.z, xv[j].z, acc[a][j]);
                acc[a][j] = fmaf(wv.w, xv[j].w, acc[a][j]);
            }
        }
    }
}

__global__ __launch_bounds__(512, 2) void kA(
    const float* __restrict__ x_in,
    const float* __restrict__ Wcl1, const float* __restrict__ bcl1,
    const float* __restrict__ Wcl2, const float* __restrict__ bcl2,
    const float* __restrict__ Wcl3, const float* __restrict__ bcl3,
    const float* __restrict__ Wcl4, const float* __restrict__ bcl4,
    const float* __restrict__ Wreg1, const float* __restrict__ breg1,
    __hip_bfloat16* __restrict__ xr, int* __restrict__ ind, float* __restrict__ out)
{
    __shared__ float act[128 * 160];   // 80 KB, swizzled transposed activations (in-place)
    __shared__ float wbuf[128 * 128];  // 64 KB, current layer weights
    __shared__ u64 argb[160];          // packed (value, 255-idx) argmax

    const int h = blockIdx.x;
    const int t = threadIdx.x;
    const int og = t >> 5;     // 0..15 row group
    const int ws = t & 31;     // 0..31 col group
    const int og8 = og << 3;

    int wbase[5], wk[5];
#pragma unroll
    for (int j = 0; j < 5; ++j) { const int w = ws * 5 + j; wbase[j] = w << 7; wk[j] = w & 31; }

    if (t < 160) argb[t] = 0ull;

    // ---- stage x: global [c][h][w] -> act (transpose + swizzle) ----
    {
        const float4* xg = reinterpret_cast<const float4*>(x_in);
#pragma unroll
        for (int k = 0; k < 10; ++k) {
            const int fi = t + (k << 9);          // 0..5119 float4s
            const int c = fi / 40, wq = fi - c * 40;
            const float4 v = xg[((size_t)c * HH + h) * 40 + wq];
            const int w0 = wq << 2;
            act[actIdx(w0 + 0, c)] = v.x;
            act[actIdx(w0 + 1, c)] = v.y;
            act[actIdx(w0 + 2, c)] = v.z;
            act[actIdx(w0 + 3, c)] = v.w;
        }
    }

    float4 wreg[8];
    const float4* Wr1 = reinterpret_cast<const float4*>(Wreg1 + (size_t)h * (256 * 128));
    loadW(wreg, Wr1, t);          // reg1 rows 0..127
    storeW(wreg, wbuf, t);
    __syncthreads();

    // ---- reg1: O=256 in two halves, output bf16 to xr[(h*W+w)*256 + o] ----
#pragma unroll
    for (int half = 0; half < 2; ++half) {
        if (half == 0) loadW(wreg, Wr1 + 4096, t);                                            // rows 128..255
        else           loadW(wreg, reinterpret_cast<const float4*>(Wcl1 + (size_t)h * 16384), t); // cl1
        float acc[8][5];
        compute128(act, wbuf, wbase, wk, og8, acc);
        const float* bp = breg1 + h * 256 + (half << 7) + og8;
        float bb[8];
#pragma unroll
        for (int a = 0; a < 8; ++a) bb[a] = bp[a];
#pragma unroll
        for (int j = 0; j < 5; ++j) {
            const int w = ws * 5 + j;
            alignas(16) unsigned short us[8];
#pragma unroll
            for (int a = 0; a < 8; ++a) {
                __hip_bfloat16 bv = __float2bfloat16(leaky(acc[a][j] + bb[a]));
                us[a] = *reinterpret_cast<const unsigned short*>(&bv);
            }
            *reinterpret_cast<uint4*>(xr + (((size_t)(h * WW + w)) << 8) + (half << 7) + og8) =
                *reinterpret_cast<const uint4*>(us);
        }
        __syncthreads();
        storeW(wreg, wbuf, t);
        __syncthreads();
    }

    // ---- cl1..cl3: in-place act update, prefetch next weights (T14) ----
    const float* Wn[3]  = { Wcl2 + (size_t)h * 16384, Wcl3 + (size_t)h * 16384,
                            Wcl4 + (size_t)h * 32896 };                       // next: cl2, cl3, cl4 rows 0..127
    const float* bcl[3] = { bcl1 + (h << 7), bcl2 + (h << 7), bcl3 + (h << 7) };
#pragma unroll
    for (int L = 0; L < 3; ++L) {
        loadW(wreg, reinterpret_cast<const float4*>(Wn[L]), t);
        float acc[8][5];
        compute128(act, wbuf, wbase, wk, og8, acc);
        float bb[8];
#pragma unroll
        for (int a = 0; a < 8; ++a) bb[a] = bcl[L][og8 + a];
        __syncthreads();           // all act/wbuf reads done
#pragma unroll
        for (int j = 0; j < 5; ++j) {
            const int w = ws * 5 + j;
            float4 lo, hi;
            lo.x = leaky(acc[0][j] + bb[0]); lo.y = leaky(acc[1][j] + bb[1]);
            lo.z = leaky(acc[2][j] + bb[2]); lo.w = leaky(acc[3][j] + bb[3]);
            hi.x = leaky(acc[4][j] + bb[4]); hi.y = leaky(acc[5][j] + bb[5]);
            hi.z = leaky(acc[6][j] + bb[6]); hi.w = leaky(acc[7][j] + bb[7]);
            const int wk31 = w & 31;
            *reinterpret_cast<float4*>(act + (w << 7) + ((((og << 1)    ) ^ wk31) << 2)) = lo;
            *reinterpret_cast<float4*>(act + (w << 7) + ((((og << 1) | 1) ^ wk31) << 2)) = hi;
        }
        storeW(wreg, wbuf, t);
        __syncthreads();
    }

    // ---- cl4: two 128-row halves; argmax only (logits never stored) ----
    const float* b4 = bcl4 + h * 257;
#pragma unroll
    for (int half = 0; half < 2; ++half) {
        if (half == 0)
            loadW(wreg, reinterpret_cast<const float4*>(Wcl4 + ((size_t)h * 257 + 128) * 128), t);
        float acc[8][5];
        compute128(act, wbuf, wbase, wk, og8, acc);
        const int rbase = (half << 7) + og8;
        float bb[8];
#pragma unroll
        for (int a = 0; a < 8; ++a) bb[a] = b4[rbase + a];
#pragma unroll
        for (int j = 0; j < 5; ++j) {
            float mv = acc[0][j] + bb[0]; int mr = rbase;
#pragma unroll
            for (int a = 1; a < 8; ++a) {
                const float v = acc[a][j] + bb[a];
                if (v > mv) { mv = v; mr = rbase + a; }
            }
            unsigned u = __float_as_uint(mv);
            u = (u & 0x80000000u) ? ~u : (u | 0x80000000u);   // monotone f32 -> u32
            const u64 key = ((u64)u << 32) | (unsigned)(255 - mr); // ties -> lowest idx
            atomicMax(&argb[ws * 5 + j], key);
        }
        __syncthreads();
        if (half == 0) { storeW(wreg, wbuf, t); __syncthreads(); }
    }

    // ---- finalize: ind + mask row (act still holds cl3 output) ----
    if (t < 160) {
        const u64 k = argb[t];
        const int idx = 255 - (int)(k & 0xFFu);
        ind[h * WW + t] = idx;
        const float* Wm = Wcl4 + ((size_t)h * 257 + 256) * 128;
        float accm = 0.f;
#pragma unroll 8
        for (int c = 0; c < 128; ++c) accm += Wm[c] * act[actIdx(t, c)];
        out[NPIX + h * WW + t] = leaky(accm + b4[256]);
    }
}

__global__ __launch_bounds__(256) void kB(
    const __hip_bfloat16* __restrict__ xr, const int* __restrict__ ind,
    const float* __restrict__ Wcm2, const float* __restrict__ bcm2,
    const float* __restrict__ Wcm3, const float* __restrict__ bcm3,
    float* __restrict__ out)
{
    const int gwave = (int)((blockIdx.x * blockDim.x + threadIdx.x) >> 6);
    const int lane = threadIdx.x & 63;
    const int nwave = (int)(gridDim.x * (blockDim.x >> 6));

    for (int n = gwave; n < NPIX; n += nwave) {
        const int h_o = n % HH, w_o = n / HH;   // xr source & output position (w-major flat)
        const int h_i = n / WW, w_i = n % WW;   // index-gather position (h-major flat)
        const int ig = ind[h_i * WW + w_i];
        const int sc = (ig >> 4) + (h_i << 4);
        const int rr = ig + (h_i << 8);

        const __hip_bfloat16* xp = xr + (size_t)(h_o * WW + w_o) * 256;
        const float* Wp = Wcm2 + (size_t)sc * 2048;

        float acc[8];
#pragma unroll
        for (int o = 0; o < 8; ++o) acc[o] = 0.f;

        const int c0 = lane * 4;
        const ushort4 xv4 = *(const ushort4*)((const unsigned short*)xp + c0);
        float xf[4];
        xf[0] = __uint_as_float((unsigned int)xv4.x << 16);
        xf[1] = __uint_as_float((unsigned int)xv4.y << 16);
        xf[2] = __uint_as_float((unsigned int)xv4.z << 16);
        xf[3] = __uint_as_float((unsigned int)xv4.w << 16);

#pragma unroll
        for (int i = 0; i < 4; ++i) {
            const float4* wrow = (const float4*)&Wp[(c0 + i) * 8];
            const float4 wa = wrow[0];
            const float4 wb_ = wrow[1];
            const float x = xf[i];
            acc[0] += x * wa.x;  acc[1] += x * wa.y;  acc[2] += x * wa.z;  acc[3] += x * wa.w;
            acc[4] += x * wb_.x; acc[5] += x * wb_.y; acc[6] += x * wb_.z; acc[7] += x * wb_.w;
        }
#pragma unroll
        for (int o = 0; o < 8; ++o) {
            float v = acc[o];
#pragma unroll
            for (int d = 32; d > 0; d >>= 1) v += __shfl_xor(v, d, 64);
            acc[o] = v;
        }
        float r = bcm3[rr];
        const float* b2 = bcm2 + (size_t)sc * 8;
        const float* w3 = Wcm3 + (size_t)rr * 8;
#pragma unroll
        for (int o = 0; o < 8; ++o) {
            const float y = leaky(acc[o] + b2[o]);
            r += y * w3[o];
        }
        if (lane == 0) {
            const float iv = (float)ind[h_o * WW + w_o];
            out[h_o * WW + w_o] = (iv + r) * (1.0f / 256.0f);
        }
    }
}

extern "C" void kernel_launch(void* const* d_in, const int* in_sizes, int n_in,
                              void* d_out, int out_size, void* d_ws, size_t ws_size,
                              hipStream_t stream)
{
    const float* x_in  = (const float*)d_in[0];
    const float* Wcl1  = (const float*)d_in[1];
    const float* bcl1  = (const float*)d_in[2];
    const float* Wcl2  = (const float*)d_in[3];
    const float* bcl2  = (const float*)d_in[4];
    const float* Wcl3  = (const float*)d_in[5];
    const float* bcl3  = (const float*)d_in[6];
    const float* Wcl4  = (const float*)d_in[7];
    const float* bcl4  = (const float*)d_in[8];
    const float* Wreg1 = (const float*)d_in[9];
    const float* breg1 = (const float*)d_in[10];
    const float* Wcm2  = (const float*)d_in[11];
    const float* bcm2  = (const float*)d_in[12];
    const float* Wcm3  = (const float*)d_in[13];
    const float* bcm3  = (const float*)d_in[14];

    float* out = (float*)d_out;

    // workspace: x_r as bf16 [448][160][256], then ind int32 [448*160]
    __hip_bfloat16* xr = (__hip_bfloat16*)d_ws;
    int* ind = (int*)((char*)d_ws + (size_t)NPIX * 256 * sizeof(__hip_bfloat16));

    kA<<<dim3(HH), dim3(512), 0, stream>>>(x_in, Wcl1, bcl1, Wcl2, bcl2, Wcl3, bcl3,
                                           Wcl4, bcl4, Wreg1, breg1, xr, ind, out);
    kB<<<dim3(1792), dim3(256), 0, stream>>>(xr, ind, Wcm2, bcm2, Wcm3, bcm3, out);
}